// Round 2
// baseline (463.767 us; speedup 1.0000x reference)
//
#include <hip/hip_runtime.h>
#include <stdint.h>

#define E_DIM 512
#define NM 24
#define NC 48      // NM * 2 (re/im interleaved)
#define NCOL 96    // q(48) + k(48)
#define B_DIM 16
#define H_DIM 4096
#define NROWS (B_DIM * H_DIM)

// ---------- K1: build C[512][96], bias d[96], and M[48][512] in one launch ----------
// blocks 0..512: C/d (block 512 = bias). blocks 513..704: M synthesis matrix.
__global__ __launch_bounds__(128)
void k_build(const float* __restrict__ Wq, const float* __restrict__ Wk,
             const float* __restrict__ bq, const float* __restrict__ bk,
             const int* __restrict__ idxq,
             float* __restrict__ C, float* __restrict__ dvec, float* __restrict__ M) {
  __shared__ float twc[E_DIM], tws[E_DIM];
  __shared__ int fj[NM];
  const int t = threadIdx.x;
  const int bid = blockIdx.x;
  if (bid >= E_DIM + 1) {
    // ---- M part: M[c][e] for gid in [0, 48*512) ----
    const int gid = (bid - (E_DIM + 1)) * 128 + t;
    const int c = gid >> 9;
    const int e = gid & (E_DIM - 1);
    const int j = c >> 1, p = c & 1;
    const int f = idxq[j];
    const float w = (f == 0 ? 1.0f : 2.0f) * (1.0f / (float)E_DIM);
    float s, cc;
    sincospif((float)((f * e) & (E_DIM - 1)) * (1.0f / 256.0f), &s, &cc);
    M[c * E_DIM + e] = p ? (-w * s) : (w * cc);
    return;
  }
  for (int i = t; i < E_DIM; i += 128) {
    float s, c;
    sincospif((float)i * (1.0f / 256.0f), &s, &c);   // angle = 2*pi*i/512
    twc[i] = c; tws[i] = s;
  }
  if (t < NM) fj[t] = idxq[t];
  __syncthreads();
  const int e = bid;                   // 0..511 = W column, 512 = bias row
  if (t >= NCOL) return;
  const int mat = t / NC;              // 0 = q, 1 = k
  const int c = t - mat * NC;
  const int j = c >> 1, p = c & 1;
  const int f = fj[j];
  float acc = 0.0f;
  if (e < E_DIM) {
    const float* __restrict__ W = mat ? Wk : Wq;
    for (int o = 0; o < E_DIM; ++o) {
      const float w = W[o * E_DIM + e];
      const int tt = (f * o) & (E_DIM - 1);
      acc = fmaf(w, p ? -tws[tt] : twc[tt], acc);
    }
    C[e * NCOL + t] = acc;
  } else {
    const float* __restrict__ bv = mat ? bk : bq;
    for (int o = 0; o < E_DIM; ++o) {
      const int tt = (f * o) & (E_DIM - 1);
      acc = fmaf(bv[o], p ? -tws[tt] : twc[tt], acc);
    }
    dvec[t] = acc;
  }
}

// ---------- K2: G[65536][96] = x[65536][512] @ C[512][96] + d ----------
// 128 threads, 8 rows x 12 cols per thread -> 80 B LDS per 192 flop (2.4 flop/B),
// register-staged prefetch of the next k-tile across the barrier.
#define GBM 128
#define GBK 32
__global__ __launch_bounds__(128)
void k_gemmG(const float* __restrict__ x, const float* __restrict__ C,
             const float* __restrict__ dvec, float* __restrict__ G) {
  __shared__ __align__(16) float xs[GBK][132];      // transposed x tile [k][row]
  __shared__ __align__(16) float cs[GBK * NCOL];    // [32][96]
  __shared__ float dsh[NCOL];
  const int t = threadIdx.x;
  const int ri = t >> 3;    // 0..15 -> rows ri*8 .. ri*8+7
  const int ci = t & 7;     // 0..7  -> cols ci*12 .. ci*12+11
  const int row0 = blockIdx.x * GBM;
  if (t < NCOL) dsh[t] = dvec[t];
  float acc[8][12];
#pragma unroll
  for (int a = 0; a < 8; ++a)
#pragma unroll
    for (int b = 0; b < 12; ++b) acc[a][b] = 0.0f;

  float4 xv[8], cv[6];
  // prologue: stage k0 = 0 tiles into registers
#pragma unroll
  for (int r = 0; r < 8; ++r) {
    const int lin = r * 128 + t;
    xv[r] = *(const float4*)&x[(row0 + (lin >> 3)) * E_DIM + ((lin & 7) << 2)];
  }
#pragma unroll
  for (int r = 0; r < 6; ++r)
    cv[r] = *(const float4*)&C[(r * 128 + t) * 4];

  for (int k0 = 0;; k0 += GBK) {
    __syncthreads();     // previous compute finished reading LDS
#pragma unroll
    for (int r = 0; r < 8; ++r) {
      const int lin = r * 128 + t;
      const int row = lin >> 3, kc = lin & 7;
      xs[kc * 4 + 0][row] = xv[r].x;
      xs[kc * 4 + 1][row] = xv[r].y;
      xs[kc * 4 + 2][row] = xv[r].z;
      xs[kc * 4 + 3][row] = xv[r].w;
    }
#pragma unroll
    for (int r = 0; r < 6; ++r)
      *(float4*)&cs[(r * 128 + t) * 4] = cv[r];
    __syncthreads();
    const bool more = (k0 + GBK) < E_DIM;
    if (more) {
      const int kn = k0 + GBK;
#pragma unroll
      for (int r = 0; r < 8; ++r) {
        const int lin = r * 128 + t;
        xv[r] = *(const float4*)&x[(row0 + (lin >> 3)) * E_DIM + kn + ((lin & 7) << 2)];
      }
#pragma unroll
      for (int r = 0; r < 6; ++r)
        cv[r] = *(const float4*)&C[kn * NCOL + (r * 128 + t) * 4];
    }
#pragma unroll 4
    for (int kk = 0; kk < GBK; ++kk) {
      const float4 xa = *(const float4*)&xs[kk][ri * 8];
      const float4 xb = *(const float4*)&xs[kk][ri * 8 + 4];
      const float4 c0 = *(const float4*)&cs[kk * NCOL + ci * 12];
      const float4 c1 = *(const float4*)&cs[kk * NCOL + ci * 12 + 4];
      const float4 c2 = *(const float4*)&cs[kk * NCOL + ci * 12 + 8];
      const float xr[8] = {xa.x, xa.y, xa.z, xa.w, xb.x, xb.y, xb.z, xb.w};
      const float cc[12] = {c0.x, c0.y, c0.z, c0.w, c1.x, c1.y, c1.z, c1.w,
                            c2.x, c2.y, c2.z, c2.w};
#pragma unroll
      for (int a = 0; a < 8; ++a)
#pragma unroll
        for (int b = 0; b < 12; ++b)
          acc[a][b] = fmaf(xr[a], cc[b], acc[a][b]);
    }
    if (!more) break;
  }
#pragma unroll
  for (int a = 0; a < 8; ++a) {
    const int row = row0 + ri * 8 + a;
#pragma unroll
    for (int b4 = 0; b4 < 3; ++b4) {
      float4 v;
      v.x = acc[a][b4 * 4 + 0] + dsh[ci * 12 + b4 * 4 + 0];
      v.y = acc[a][b4 * 4 + 1] + dsh[ci * 12 + b4 * 4 + 1];
      v.z = acc[a][b4 * 4 + 2] + dsh[ci * 12 + b4 * 4 + 2];
      v.w = acc[a][b4 * 4 + 3] + dsh[ci * 12 + b4 * 4 + 3];
      *(float4*)&G[row * NCOL + ci * 12 + b4 * 4] = v;
    }
  }
}

// ---------- K3a: partial S over h-chunks: Sp[b][hc][24][24]{re,im} ----------
// stage the 128x96 G slab in LDS (coalesced float4), then broadcast-read it.
__global__ __launch_bounds__(576)
void k_spart(const float* __restrict__ G, float* __restrict__ Sp) {
  __shared__ __align__(16) float gs[128 * NCOL];    // 48 KB
  const int t = threadIdx.x;           // 0..575 = (x,y)
  const int xx = t / NM, yy = t - xx * NM;
  const int bc = blockIdx.x;           // b*32 + hc
  const int b = bc >> 5, hc = bc & 31;
  const int r0 = b * H_DIM + hc * 128;
  const float4* __restrict__ g4 = (const float4*)G;
#pragma unroll
  for (int r = 0; r < 6; ++r) {
    const int idx = t + r * 576;
    if (idx < 128 * NCOL / 4)
      ((float4*)gs)[idx] = g4[r0 * (NCOL / 4) + idx];
  }
  __syncthreads();
  float sre = 0.0f, sim = 0.0f;
  for (int h = 0; h < 128; ++h) {
    const float2 q = *(const float2*)&gs[h * NCOL + 2 * xx];
    const float2 k = *(const float2*)&gs[h * NCOL + NC + 2 * yy];
    sre += q.x * k.x - q.y * k.y;      // complex product, no conjugation
    sim += q.x * k.y + q.y * k.x;
  }
  ((float2*)Sp)[bc * 576 + t] = make_float2(sre, sim);
}

// ---------- K3b: reduce chunks, |.|, row softmax -> att[b][24][24] ----------
__global__ __launch_bounds__(576)
void k_att(const float* __restrict__ Sp, float* __restrict__ att) {
  __shared__ float mag[576];
  __shared__ float ex[576];
  const int t = threadIdx.x;
  const int b = blockIdx.x;
  float sre = 0.0f, sim = 0.0f;
  const float2* in2 = (const float2*)Sp;
  for (int hc = 0; hc < 32; ++hc) {
    const float2 v = in2[(b * 32 + hc) * 576 + t];
    sre += v.x; sim += v.y;
  }
  mag[t] = sqrtf(sre * sre + sim * sim);
  __syncthreads();
  const int xx = t / NM;
  float m = -1e30f;
  for (int k = 0; k < NM; ++k) m = fmaxf(m, mag[xx * NM + k]);
  const float e = expf(mag[t] - m);
  ex[t] = e;
  __syncthreads();
  float s = 0.0f;
  for (int k = 0; k < NM; ++k) s += ex[xx * NM + k];
  att[b * 576 + t] = e / s;
}

// ---------- K4: Z[row][48] = att[b] applied to K-spectrum ----------
__global__ __launch_bounds__(128)
void k_z(const float* __restrict__ G, const float* __restrict__ att,
         float* __restrict__ Z) {
  __shared__ float at[576];
  const int t = threadIdx.x;
  const int row = blockIdx.x * 128 + t;
  const int b = row >> 12;             // 4096 rows per batch
  for (int i = t; i < 576; i += 128) at[i] = att[b * 576 + i];
  __syncthreads();
  float gk[NC];
#pragma unroll
  for (int i = 0; i < NC / 4; ++i) {
    const float4 v = *(const float4*)&G[row * NCOL + NC + i * 4];
    gk[i * 4 + 0] = v.x; gk[i * 4 + 1] = v.y; gk[i * 4 + 2] = v.z; gk[i * 4 + 3] = v.w;
  }
  float z[NC];
#pragma unroll
  for (int xx = 0; xx < NM; ++xx) {
    float zr = 0.0f, zi = 0.0f;
#pragma unroll
    for (int y = 0; y < NM; ++y) {
      const float a = at[xx * NM + y];
      zr = fmaf(a, gk[2 * y], zr);
      zi = fmaf(a, gk[2 * y + 1], zi);
    }
    z[2 * xx] = zr; z[2 * xx + 1] = zi;
  }
#pragma unroll
  for (int i = 0; i < NC / 4; ++i) {
    float4 v;
    v.x = z[i * 4]; v.y = z[i * 4 + 1]; v.z = z[i * 4 + 2]; v.w = z[i * 4 + 3];
    *(float4*)&Z[row * NC + i * 4] = v;
  }
}

// ---------- K5: out[65536][512] = Z[65536][48] @ M[48][512] ----------
#define OBM 128
#define OBN 128
__global__ __launch_bounds__(256)
void k_out(const float* __restrict__ Z, const float* __restrict__ M,
           float* __restrict__ out) {
  __shared__ __align__(16) float zs[NC][OBM + 4];
  __shared__ __align__(16) float ms[NC * OBN];
  const int t = threadIdx.x;
  const int ri = t >> 4, ci = t & 15;       // 8 rows x 8 cols per thread
  const int row0 = (blockIdx.x >> 2) * OBM;
  const int e0 = (blockIdx.x & 3) * OBN;
#pragma unroll
  for (int it = 0; it < 6; ++it) {          // Z tile 128x48
    const int idx = t + it * 256;
    const int row = idx / 12, kc = idx - row * 12;
    const float4 v = *(const float4*)&Z[(row0 + row) * NC + kc * 4];
    zs[kc * 4 + 0][row] = v.x;
    zs[kc * 4 + 1][row] = v.y;
    zs[kc * 4 + 2][row] = v.z;
    zs[kc * 4 + 3][row] = v.w;
  }
#pragma unroll
  for (int it = 0; it < 6; ++it) {          // M tile 48x128
    const int idx = t + it * 256;
    const int k = idx >> 5, ec = idx & 31;
    *(float4*)&ms[k * OBN + ec * 4] = *(const float4*)&M[k * E_DIM + e0 + ec * 4];
  }
  __syncthreads();
  float acc[8][8];
#pragma unroll
  for (int a = 0; a < 8; ++a)
#pragma unroll
    for (int b = 0; b < 8; ++b) acc[a][b] = 0.0f;
#pragma unroll 4
  for (int k = 0; k < NC; ++k) {
    const float4 za = *(const float4*)&zs[k][ri * 8];
    const float4 zb = *(const float4*)&zs[k][ri * 8 + 4];
    const float4 ma = *(const float4*)&ms[k * OBN + ci * 8];
    const float4 mb = *(const float4*)&ms[k * OBN + ci * 8 + 4];
    const float zr[8] = {za.x, za.y, za.z, za.w, zb.x, zb.y, zb.z, zb.w};
    const float mr[8] = {ma.x, ma.y, ma.z, ma.w, mb.x, mb.y, mb.z, mb.w};
#pragma unroll
    for (int a = 0; a < 8; ++a)
#pragma unroll
      for (int b = 0; b < 8; ++b)
        acc[a][b] = fmaf(zr[a], mr[b], acc[a][b]);
  }
#pragma unroll
  for (int a = 0; a < 8; ++a) {
    const int row = row0 + ri * 8 + a;
    float4 v0, v1;
    v0.x = acc[a][0]; v0.y = acc[a][1]; v0.z = acc[a][2]; v0.w = acc[a][3];
    v1.x = acc[a][4]; v1.y = acc[a][5]; v1.z = acc[a][6]; v1.w = acc[a][7];
    *(float4*)&out[row * E_DIM + e0 + ci * 8] = v0;
    *(float4*)&out[row * E_DIM + e0 + ci * 8 + 4] = v1;
  }
}

extern "C" void kernel_launch(void* const* d_in, const int* in_sizes, int n_in,
                              void* d_out, int out_size, void* d_ws, size_t ws_size,
                              hipStream_t stream) {
  const float* x  = (const float*)d_in[0];
  const float* Wq = (const float*)d_in[1];
  const float* bq = (const float*)d_in[2];
  const float* Wk = (const float*)d_in[3];
  const float* bk = (const float*)d_in[4];
  // d_in[5] (Wv), d_in[6] (bv): dead code in reference, never read
  const int* idxq = (const int*)d_in[7];
  float* out = (float*)d_out;
  float* ws = (float*)d_ws;

  // ws layout (floats): C 49152 | d 128 | M 24576 | att 9216 | Sp 589824 | Z 3145728
  float* C   = ws;
  float* dv  = ws + 49152;
  float* M   = ws + 49280;
  float* att = ws + 73856;
  float* Sp  = ws + 83072;
  float* Z   = ws + 672896;          // total ~14.6 MB of ws
  float* G   = out;                  // park G[65536][96] in d_out; dead before k_out writes

  k_build<<<E_DIM + 1 + (NC * E_DIM) / 128, 128, 0, stream>>>(Wq, Wk, bq, bk, idxq, C, dv, M);
  k_gemmG<<<NROWS / GBM, 128, 0, stream>>>(x, C, dv, G);
  k_spart<<<B_DIM * 32, 576, 0, stream>>>(G, Sp);
  k_att<<<B_DIM, 576, 0, stream>>>(Sp, att);
  k_z<<<NROWS / 128, 128, 0, stream>>>(G, att, Z);
  k_out<<<(NROWS / OBM) * (E_DIM / OBN), 256, 0, stream>>>(Z, M, out);
}